// Round 6
// baseline (187.252 us; speedup 1.0000x reference)
//
#include <hip/hip_runtime.h>
#include <hip/hip_bf16.h>
#include <hip/hip_fp16.h>
#include <math.h>

// ---------------------------------------------------------------------------
// TaggingQuantizer: cosine-distance VQ assignment + loss + pos/neg reorder.
//   z: (65536, 256) f32,  W: (1024, 256) f32
//   out: emb (1024*256) | label (1024) | loss (1)   all f32, flat-concat.
//
// R15: DIAGNOSTIC ROUND. Real pipeline = exact R12 (best known: k_score 65us,
//      total 150.5us). Appended ONE ablated dispatch k_score<1> AFTER k_emit:
//      staging + 4x KLOOP + minimal liveness sink (no bestk reduce, no ADMIT,
//      no slots, no compaction; ssq -> dummy store so loss is untouched).
//      Readout: V1_duration = dur_us - 150.5.
//      Decision tree (pre-committed):
//        V1 >= 45us -> core-bound (KLOOP loads): R16 = B-LDS pipelined KLOOP.
//        V1 <= 40us -> selection-bound (ADMIT/bestk/compaction ~25-45us):
//                      R16 = register-threshold ADMIT + parallel compaction.
//      Rationale: R10-R14 falsified bank-conflict / occupancy / dtype /
//      MFMA-shape / reg-budget theories; pipe-work sum (~60us) ~= duration
//      => phases serialized; need to know WHICH phase owns the wall time.
// ---------------------------------------------------------------------------

typedef unsigned short u16;
typedef unsigned int   u32;
typedef unsigned long long u64;
typedef __attribute__((ext_vector_type(8))) _Float16 f16x8; // 8 f16 (4 VGPR)
typedef __attribute__((ext_vector_type(4))) float f32x4;

#define N_E   1024
#define E_DIM 256
#define N_TOK 65536
#define BETA  0.25f
#define CAPL  24      // LDS slots/token
#define CAPG  8       // global candidates/token
#define D_ADM 0.025f  // admission margin (> 2*E_wc, E_wc <= ||z||*2^-11 = 0.0093)
#define D_FIL 0.026f  // final filter: D_ADM + fix16 trunc (4.9e-4) + slack

// ws layout (bytes)
#define WS_INVNORM 0          // float[1024]
#define WS_NORMW   4096       // float[1024]
#define WS_MASK    8192       // int[1024]
#define WS_LACC    12288      // double[256] -> 14336
#define WS_WCNT    14336      // u32 worklist counter
#define WS_WCNT2   14340      // u32 overflow-list counter
#define WS_WSW     16384      // u16[1024*256] swizzled f16 Wn (512 KB)
#define WS_CNT     540672     // u32[65536]
#define WS_CAND    802816     // u16[65536*CAPG] (1 MB) -> 1851392
#define WS_WLIST   1851392    // u32[65536] -> 2113536
#define WS_WLIST2  2113536    // u32[65536] -> 2375680

static __device__ __forceinline__ u32 pk2fh(float a, float b) { // packed f32->f16 RNE
    __half2 p = __float22half2_rn(make_float2(a, b));
    return *reinterpret_cast<u32*>(&p);
}
static __device__ __forceinline__ u32 keyenc(float f) { // monotone f32->u32
    u32 u = __float_as_uint(f);
    return u ^ (u32)(((int)u >> 31) | 0x80000000);
}
static __device__ __forceinline__ float keydec(u32 k) {
    u32 u = (k & 0x80000000u) ? (k ^ 0x80000000u) : ~k;
    return __uint_as_float(u);
}

// --------------------------------------------------------------------------
// K1 prep: norms + swizzled f16 normalized W in MFMA B-fragment order.
// Zeroes mask/lacc/wcnt/wcnt2 (ws re-poisoned each call).
// --------------------------------------------------------------------------
__global__ void k_prep(const float* __restrict__ W, u16* __restrict__ Wsw,
                       float* __restrict__ inv_norm, float* __restrict__ normW,
                       int* __restrict__ mask, double* __restrict__ lacc,
                       u32* __restrict__ wcnt, u32* __restrict__ wcnt2) {
    const int n = blockIdx.x;      // 1024
    const int l = threadIdx.x;     // 64
    const float4 v = reinterpret_cast<const float4*>(W + (size_t)n * E_DIM)[l];
    float s = v.x * v.x + v.y * v.y + v.z * v.z + v.w * v.w;
#pragma unroll
    for (int sh = 1; sh < 64; sh <<= 1) s += __shfl_xor(s, sh, 64);
    const float nw = sqrtf(s), inv = 1.0f / nw;
    if (l == 0) {
        inv_norm[n] = inv; normW[n] = nw; mask[n] = 0;
        if (n < 256) lacc[n] = 0.0;
        if (n == 0) { *wcnt = 0u; *wcnt2 = 0u; }
    }
    const int o = l >> 1;          // k-octet 0..31
    const int kc = o >> 2, q = o & 3;
    const size_t base =
        (((((size_t)(n >> 7) * 8 + kc) * 8 + ((n >> 4) & 7)) * 64 +
          (q * 16 + (n & 15))) * 8) + (l & 1) * 4;
    u32* dst = reinterpret_cast<u32*>(Wsw + base);
    dst[0] = pk2fh(v.x * inv, v.y * inv);
    dst[1] = pk2fh(v.z * inv, v.w * inv);
}

// --------------------------------------------------------------------------
// K2 score: 128 tokens x 1024 codes, 512 threads = 8 waves
// (2 mq x 4 nq, 4x4 acc/wave over 256-code chunks). One barrier after
// chunk 0 (tight bestk); chunks 1-3 stream barrier-free.
// Template V: 3 = full/real kernel (R12-identical). 1 = ablation variant:
// staging + 4x KLOOP + cheap prescreen sink only (dummy stores; does not
// touch lacc/mask/counters; safe to run after the real pipeline).
// --------------------------------------------------------------------------
template<int V>
__global__ __launch_bounds__(512, 4)
void k_score(const float* __restrict__ z, const u16* __restrict__ Wsw,
             const float* __restrict__ normW, u16* __restrict__ cand_g,
             u32* __restrict__ cnt_g, int* __restrict__ mask,
             u32* __restrict__ wlist, u32* __restrict__ wcnt,
             u32* __restrict__ wlist2, u32* __restrict__ wcnt2,
             double* __restrict__ lacc) {
    __shared__ __align__(16) u16 A_sw[32768];   // [kc(8)][mt(8)][lane(64)][j(8)]
    __shared__ u32 bestk[128];
    __shared__ u32 cnt[128];
    __shared__ u32 slots[128 * CAPL];           // (fix16 score<<16) | code

    const int t    = threadIdx.x;
    const int lane = t & 63;
    const int w    = t >> 6;
    const size_t tok_base = (size_t)blockIdx.x * 128;

    if (t < 128) { bestk[t] = 0u; cnt[t] = 0u; }

    // ---- staging (l[2:0] -> m&7: conflict-free ds_write) + fused sum(z^2) --
    float ssq = 0.f;
#pragma unroll
    for (int i = 0; i < 8; i++) {
        const int m = ((i & 1) << 6) | (w << 3) | (lane & 7);    // token row
        const int o = ((i >> 1) << 3) | (lane >> 3);             // k-octet
        const float* zp = z + (tok_base + m) * E_DIM + o * 8;
        const float4 v0 = reinterpret_cast<const float4*>(zp)[0];
        const float4 v1 = reinterpret_cast<const float4*>(zp)[1];
        ssq += v0.x * v0.x + v0.y * v0.y + v0.z * v0.z + v0.w * v0.w
             + v1.x * v1.x + v1.y * v1.y + v1.z * v1.z + v1.w * v1.w;
        uint4 d;
        d.x = pk2fh(v0.x, v0.y);
        d.y = pk2fh(v0.z, v0.w);
        d.z = pk2fh(v1.x, v1.y);
        d.w = pk2fh(v1.z, v1.w);
        const int kc = o >> 2, q = o & 3, col = m & 15, mt = m >> 4;
        *reinterpret_cast<uint4*>(A_sw + ((size_t)((kc * 8 + mt) * 64 + q * 16 + col)) * 8) = d;
    }
#pragma unroll
    for (int sh = 1; sh < 64; sh <<= 1) ssq += __shfl_xor(ssq, sh, 64);
    if constexpr (V == 3) {
        if (lane == 0) atomicAdd(&lacc[(blockIdx.x * 8 + w) & 255], (double)ssq);
    } else {
        // dummy sink: keeps staging + ssq live without touching lacc
        if (lane == 0) wlist[((u32)tok_base + (u32)w) & 65535u] = __float_as_uint(ssq);
    }
    __syncthreads();

    const int mq = w >> 2;                 // token half (64 tokens, mi=4)
    const int nq = w & 3;                  // code 64-group within chunk (ni=4)
    const int q = lane >> 4, col = lane & 15;
    const u16* wb = Wsw + ((size_t)((nq >> 1) * 64 + (nq & 1) * 4)) * 512
                        + (size_t)lane * 8;

    f32x4 acc[4][4];
    float psink = 0.f;   // V==1 liveness sink

#define ZERO_ACC() { _Pragma("unroll") for (int mi = 0; mi < 4; mi++) \
    _Pragma("unroll") for (int ni = 0; ni < 4; ni++) { \
        f32x4 zf = {0.f, 0.f, 0.f, 0.f}; acc[mi][ni] = zf; } }

#define KLOOP(NB2) { \
    __builtin_amdgcn_s_setprio(1); \
    _Pragma("unroll 4") \
    for (int kc = 0; kc < 8; kc++) { \
        f16x8 bf[4], af[4]; \
        _Pragma("unroll") for (int ni = 0; ni < 4; ni++) \
            bf[ni] = *reinterpret_cast<const f16x8*>( \
                wb + (size_t)((NB2) * 128 + kc * 8 + ni) * 512); \
        _Pragma("unroll") for (int mi = 0; mi < 4; mi++) \
            af[mi] = *reinterpret_cast<const f16x8*>( \
                A_sw + ((size_t)((kc * 8 + mq * 4 + mi) * 64 + lane)) * 8); \
        _Pragma("unroll") for (int mi = 0; mi < 4; mi++) \
        _Pragma("unroll") for (int ni = 0; ni < 4; ni++) \
            acc[mi][ni] = __builtin_amdgcn_mfma_f32_16x16x32_f16( \
                af[mi], bf[ni], acc[mi][ni], 0, 0, 0); } \
    __builtin_amdgcn_s_setprio(0); }

// max-prescreen: one fused max + compare skips the branchy per-ni admission
// checks (and folds 4 atomicMax into 1) in the common no-admission case.
#define ADMIT(NB2, DO_MAX) { \
    _Pragma("unroll") for (int mi = 0; mi < 4; mi++) \
    _Pragma("unroll") for (int r = 0; r < 4; r++) { \
        const int tk = mq * 64 + mi * 16 + q * 4 + r; \
        const float thr = keydec(bestk[tk]) - D_ADM; \
        const float vmax = fmaxf(fmaxf(acc[mi][0][r], acc[mi][1][r]), \
                                 fmaxf(acc[mi][2][r], acc[mi][3][r])); \
        if (vmax >= thr) { \
            if (DO_MAX) atomicMax(&bestk[tk], keyenc(vmax)); \
            _Pragma("unroll") for (int ni = 0; ni < 4; ni++) { \
                const float v = acc[mi][ni][r]; \
                if (v >= thr) { \
                    const int code = ((NB2) * 16 + nq * 4 + ni) * 16 + col; \
                    const u32 sl = atomicAdd(&cnt[tk], 1u); \
                    if (sl < CAPL) { \
                        const float vc = fminf(fmaxf((v + 16.f) * 2048.f, 0.f), 65535.f); \
                        slots[tk * CAPL + sl] = ((u32)vc << 16) | (u32)code; \
                    } } } } } }

// V==1 sink: minimal consumption of all 64 acc values (prescreen-equivalent
// fmax tree + one add per position); no LDS reads, no atomics, no branches.
#define PSINK() { \
    _Pragma("unroll") for (int mi = 0; mi < 4; mi++) \
    _Pragma("unroll") for (int r = 0; r < 4; r++) { \
        const float vmax = fmaxf(fmaxf(acc[mi][0][r], acc[mi][1][r]), \
                                 fmaxf(acc[mi][2][r], acc[mi][3][r])); \
        psink += vmax; } }

    // ---- chunk 0 ----
    ZERO_ACC();
    KLOOP(0);
    if constexpr (V == 3) {
#pragma unroll
        for (int mi = 0; mi < 4; mi++)
#pragma unroll
            for (int r = 0; r < 4; r++) {
                float m0 = fmaxf(fmaxf(acc[mi][0][r], acc[mi][1][r]),
                                 fmaxf(acc[mi][2][r], acc[mi][3][r]));
#pragma unroll
                for (int sh = 1; sh < 16; sh <<= 1)
                    m0 = fmaxf(m0, __shfl_xor(m0, sh, 64));
                if (col == 0)
                    atomicMax(&bestk[mq * 64 + mi * 16 + q * 4 + r], keyenc(m0));
            }
        __syncthreads();   // bestk now tight over 256 codes
        ADMIT(0, 0);
    } else {
        PSINK();
    }

    // ---- chunks 1-3: barrier-free streaming ----
#pragma unroll 1
    for (int nb2 = 1; nb2 < 4; nb2++) {
        ZERO_ACC();
        KLOOP(nb2);
        if constexpr (V == 3) { ADMIT(nb2, 1); } else { PSINK(); }
    }
#undef ZERO_ACC
#undef KLOOP
#undef ADMIT
#undef PSINK

    if constexpr (V != 3) {
        // dummy sink store; runs after the real pipeline consumed wlist.
        wlist[((u32)tok_base + (u32)t) & 65535u] = __float_as_uint(psink);
        return;
    }

    __syncthreads();
    // ---- compaction: m==1 -> finish; 2..CAPG -> wlist; else -> wlist2 ----
    if (t < 128) {
        const size_t tokg = tok_base + t;
        const u32 c = cnt[t];
        const float best = keydec(bestk[t]);
        bool amb = false, ovf = false;
        float xacc = 0.f;
        if (c > CAPL) {
            ovf = true;                                  // rare: full scan
        } else {
            const float thrf = best - D_FIL;
            u16 loc[CAPG]; u32 m = 0;
            for (u32 i = 0; i < c; i++) {
                const u32 s2 = slots[t * CAPL + i];
                const float ap = (float)(s2 >> 16) * (1.0f / 2048.0f) - 16.0f;
                if (ap >= thrf) { if (m < CAPG) loc[m] = (u16)(s2 & 0xFFFFu); m++; }
            }
            if (m == 1) {
                const int bi = loc[0];
                mask[bi] = 1;                            // benign race
                const float nw = normW[bi];
                xacc = fmaf(-2.0f * best, nw, nw * nw);  // -2 z.Wbi + |Wbi|^2
            } else if (m <= CAPG) {
                for (u32 i = 0; i < m; i++) cand_g[tokg * CAPG + i] = loc[i];
                cnt_g[tokg] = m; amb = true;
            } else {
                ovf = true;
            }
        }
        // ambiguous -> wlist
        {
            const u64 bal = __ballot(amb);
            u32 base = 0;
            if (lane == 0 && bal) base = atomicAdd(wcnt, (u32)__popcll(bal));
            base = (u32)__shfl((int)base, 0, 64);
            if (amb) wlist[base + (u32)__popcll(bal & ((1ull << lane) - 1ull))] = (u32)tokg;
        }
        // overflow -> wlist2
        {
            const u64 bal = __ballot(ovf);
            u32 base = 0;
            if (lane == 0 && bal) base = atomicAdd(wcnt2, (u32)__popcll(bal));
            base = (u32)__shfl((int)base, 0, 64);
            if (ovf) wlist2[base + (u32)__popcll(bal & ((1ull << lane) - 1ull))] = (u32)tokg;
        }
        float xs = xacc;
#pragma unroll
        for (int sh = 1; sh < 64; sh <<= 1) xs += __shfl_xor(xs, sh, 64);
        if (lane == 0) atomicAdd(&lacc[(blockIdx.x * 2 + w) & 255], (double)xs);
    }
}

// --------------------------------------------------------------------------
// K3 pick (fused): phase 1 = wlist tokens (sc in [2,CAPG]), 16 lanes/token,
// grid-stride; phase 2 = overflow tokens (rare) block-parallel exact full
// scan (uniform trip count -> internal __syncthreads is safe after the
// divergent phase-1 loop reconverges).
// --------------------------------------------------------------------------
__global__ __launch_bounds__(256)
void k_pick(const float* __restrict__ z, const float* __restrict__ W,
            const float* __restrict__ inv_norm, const float* __restrict__ normW,
            const u16* __restrict__ cand_g, const u32* __restrict__ cnt_g,
            const u32* __restrict__ wlist, const u32* __restrict__ wcnt,
            const u32* __restrict__ wlist2, const u32* __restrict__ wcnt2,
            int* __restrict__ mask, double* __restrict__ lacc) {
    __shared__ float zrow[E_DIM];
    __shared__ float gbv[16], gbp[16];
    __shared__ int   gbi[16];
    const int t = threadIdx.x, lane = t & 63;
    const int gl = t & 15, grp = t >> 4;

    // ---- phase 1: ambiguous tokens ----
    {
        const u32 total = *wcnt;
        float xs = 0.f;
        for (u32 i = blockIdx.x * 16 + grp; i < total; i += 1024 * 16) {
            const size_t tok = wlist[i];
            float4 zv[4];
#pragma unroll
            for (int j = 0; j < 4; j++)
                zv[j] = reinterpret_cast<const float4*>(z + tok * E_DIM)[j * 16 + gl];
            const int n_it = (int)cnt_g[tok];
            float bv = -3.4e38f, bp = 0.f;
            int bi = 0x7FFFFFFF;
#pragma unroll 1
            for (int k2 = 0; k2 < n_it; k2++) {
                const int c = (int)cand_g[tok * CAPG + k2];
                float p = 0.f;
#pragma unroll
                for (int j = 0; j < 4; j++) {
                    const float4 wv = reinterpret_cast<const float4*>(W + (size_t)c * E_DIM)[j * 16 + gl];
                    p += zv[j].x * wv.x + zv[j].y * wv.y + zv[j].z * wv.z + zv[j].w * wv.w;
                }
#pragma unroll
                for (int sh = 1; sh < 16; sh <<= 1) p += __shfl_xor(p, sh, 64);
                const float s = p * inv_norm[c];
                if (s > bv || (s == bv && c < bi)) { bv = s; bi = c; bp = p; }
            }
            if (gl == 0) {
                mask[bi] = 1;
                xs += fmaf(-2.0f, bp, normW[bi] * normW[bi]);
            }
        }
        xs += __shfl_xor(xs, 16, 64);
        xs += __shfl_xor(xs, 32, 64);
        if (lane == 0) atomicAdd(&lacc[(blockIdx.x * 4 + (t >> 6)) & 255], (double)xs);
    }

    // ---- phase 2: overflow tokens -- block-parallel exact full scan.
    // 16 groups x 64 codes each (2 codes in flight), LDS merge with
    // ascending-index ties. Trip count uniform across the block.
    {
        const u32 total2 = *wcnt2;
        for (u32 i = blockIdx.x; i < total2; i += 1024) {
            const size_t tok = wlist2[i];
            __syncthreads();              // protect zrow reuse / phase boundary
            zrow[t] = z[tok * E_DIM + t];
            __syncthreads();
            float4 zv[4];
#pragma unroll
            for (int j = 0; j < 4; j++)
                zv[j] = reinterpret_cast<const float4*>(zrow)[j * 16 + gl];
            float bv = -3.4e38f, bp = 0.f;
            int bi = 0x7FFFFFFF;
#pragma unroll 1
            for (int k2 = 0; k2 < 64; k2 += 2) {
                const int c0 = grp * 64 + k2, c1 = c0 + 1;
                float p0 = 0.f, p1 = 0.f;
#pragma unroll
                for (int j = 0; j < 4; j++) {
                    const float4 w0 = reinterpret_cast<const float4*>(W + (size_t)c0 * E_DIM)[j * 16 + gl];
                    const float4 w1 = reinterpret_cast<const float4*>(W + (size_t)c1 * E_DIM)[j * 16 + gl];
                    p0 += zv[j].x * w0.x + zv[j].y * w0.y + zv[j].z * w0.z + zv[j].w * w0.w;
                    p1 += zv[j].x * w1.x + zv[j].y * w1.y + zv[j].z * w1.z + zv[j].w * w1.w;
                }
#pragma unroll
                for (int sh = 1; sh < 16; sh <<= 1) {
                    p0 += __shfl_xor(p0, sh, 64);
                    p1 += __shfl_xor(p1, sh, 64);
                }
                const float s0 = p0 * inv_norm[c0];
                const float s1 = p1 * inv_norm[c1];
                if (s0 > bv || (s0 == bv && c0 < bi)) { bv = s0; bi = c0; bp = p0; }
                if (s1 > bv || (s1 == bv && c1 < bi)) { bv = s1; bi = c1; bp = p1; }
            }
            if (gl == 0) { gbv[grp] = bv; gbi[grp] = bi; gbp[grp] = bp; }
            __syncthreads();
            if (t == 0) {
                float fb = gbv[0], fp = gbp[0];
                int fi = gbi[0];
                for (int g2 = 1; g2 < 16; g2++) {
                    const float v2 = gbv[g2];
                    const int i2 = gbi[g2];
                    if (v2 > fb || (v2 == fb && i2 < fi)) { fb = v2; fi = i2; fp = gbp[g2]; }
                }
                mask[fi] = 1;
                atomicAdd(&lacc[tok & 255],
                          (double)fmaf(-2.0f, fp, normW[fi] * normW[fi]));
            }
        }
    }
}

// --------------------------------------------------------------------------
// K4 emit (fused rank): each block redundantly reduces mask for prefix(e)
// and total; writes emb row + label. Block 0 finalizes loss.
// --------------------------------------------------------------------------
__global__ __launch_bounds__(256)
void k_emit(const float* __restrict__ W, const int* __restrict__ mask,
            const double* __restrict__ lacc, float* __restrict__ out) {
    __shared__ int    redp[256], redt[256];
    __shared__ double dred[256];
    const int e = blockIdx.x;              // 1024
    const int t = threadIdx.x;             // 256
    const int4 mv = reinterpret_cast<const int4*>(mask)[t];
    const int b = t * 4;
    redt[t] = mv.x + mv.y + mv.z + mv.w;
    redp[t] = (b + 0 < e ? mv.x : 0) + (b + 1 < e ? mv.y : 0) +
              (b + 2 < e ? mv.z : 0) + (b + 3 < e ? mv.w : 0);
    if (e == 0) dred[t] = lacc[t];
    __syncthreads();
#pragma unroll
    for (int s2 = 128; s2 > 0; s2 >>= 1) {
        if (t < s2) {
            redp[t] += redp[t + s2];
            redt[t] += redt[t + s2];
            if (e == 0) dred[t] += dred[t + s2];
        }
        __syncthreads();
    }
    const int prefix = redp[0], total = redt[0];
    const int m = mask[e];
    const int r = m ? prefix : (total + e - prefix);
    out[(size_t)r * E_DIM + t] = W[(size_t)e * E_DIM + t];
    if (t == 0) out[(size_t)N_E * E_DIM + r] = m ? 1.0f : 0.0f;
    if (e == 0 && t == 0) {
        const double mse = dred[0] / (double)((size_t)N_TOK * E_DIM);
        out[(size_t)N_E * E_DIM + N_E] = (float)((1.0 + (double)BETA) * mse);
    }
}

// --------------------------------------------------------------------------
extern "C" void kernel_launch(void* const* d_in, const int* in_sizes, int n_in,
                              void* d_out, int out_size, void* d_ws, size_t ws_size,
                              hipStream_t stream) {
    const float* z = (const float*)d_in[0];
    const float* W = (const float*)d_in[1];
    float* out = (float*)d_out;
    char* ws = (char*)d_ws;

    float*  inv_norm = (float*)(ws + WS_INVNORM);
    float*  normW    = (float*)(ws + WS_NORMW);
    int*    mask     = (int*)(ws + WS_MASK);
    double* lacc     = (double*)(ws + WS_LACC);
    u32*    wcnt     = (u32*)(ws + WS_WCNT);
    u32*    wcnt2    = (u32*)(ws + WS_WCNT2);
    u16*    Wsw      = (u16*)(ws + WS_WSW);
    u32*    cnt      = (u32*)(ws + WS_CNT);
    u16*    cand     = (u16*)(ws + WS_CAND);
    u32*    wlist    = (u32*)(ws + WS_WLIST);
    u32*    wlist2   = (u32*)(ws + WS_WLIST2);

    k_prep <<<N_E, 64, 0, stream>>>(W, Wsw, inv_norm, normW, mask, lacc,
                                    wcnt, wcnt2);
    k_score<3><<<N_TOK / 128, 512, 0, stream>>>(z, Wsw, normW, cand, cnt, mask,
                                                wlist, wcnt, wlist2, wcnt2, lacc);
    k_pick <<<1024, 256, 0, stream>>>(z, W, inv_norm, normW, cand, cnt,
                                      wlist, wcnt, wlist2, wcnt2, mask, lacc);
    k_emit <<<N_E, 256, 0, stream>>>(W, mask, lacc, out);
    // --- diagnostic ablation dispatch (after all consumers; dummy sinks) ---
    k_score<1><<<N_TOK / 128, 512, 0, stream>>>(z, Wsw, normW, cand, cnt, mask,
                                                wlist, wcnt, wlist2, wcnt2, lacc);
}

// Round 7
// 184.358 us; speedup vs baseline: 1.0157x; 1.0157x over previous
//
#include <hip/hip_runtime.h>
#include <hip/hip_bf16.h>
#include <hip/hip_fp16.h>
#include <math.h>

// ---------------------------------------------------------------------------
// TaggingQuantizer: cosine-distance VQ assignment + loss + pos/neg reorder.
//   z: (65536, 256) f32,  W: (1024, 256) f32
//   out: emb (1024*256) | label (1024) | loss (1)   all f32, flat-concat.
//
// R16: m97-structure KLOOP. R15's ablation proved selection is FREE
//      (V1 staging+KLOOP = 72.7us ~= full kernel) -> core-bound in the
//      B-load path: per-kc 4 L2 loads, 4-deep, serialized vs MFMA.
//      True MFMA floor (per-SIMD 19.4 cyc/mfma from the 2075 TF ubench,
//      rule #14) = 16.6us; kernel ran at ~23% of it.
//      Fix: B staged global->LDS via __builtin_amdgcn_global_load_lds
//      (width 16), double-buffered at kc granularity (16 KB tiles), ONE
//      barrier per kc (issue next-stage -> ds_read+MFMA current -> barrier
//      drains vmcnt+lgkmcnt -> swap). Wsw relaid so each (chunk,kc) slice
//      is contiguous. B read ONCE per block from L2 (was 2x per block,
//      per-wave). LDS 109 KB -> 1 block/CU (8 waves) -- HK-8-phase regime.
//      Selection (bestk/ADMIT/slots/compaction) unchanged; f16 + D_ADM
//      0.025 unchanged (R12-verified).
// ---------------------------------------------------------------------------

typedef unsigned short u16;
typedef unsigned int   u32;
typedef unsigned long long u64;
typedef __attribute__((ext_vector_type(8))) _Float16 f16x8; // 8 f16 (4 VGPR)
typedef __attribute__((ext_vector_type(4))) float f32x4;

#define N_E   1024
#define E_DIM 256
#define N_TOK 65536
#define BETA  0.25f
#define CAPL  24      // LDS slots/token
#define CAPG  8       // global candidates/token
#define D_ADM 0.025f  // admission margin (> 2*E_wc, E_wc <= ||z||*2^-11 = 0.0093)
#define D_FIL 0.026f  // final filter: D_ADM + fix16 trunc (4.9e-4) + slack

// ws layout (bytes)
#define WS_INVNORM 0          // float[1024]
#define WS_NORMW   4096       // float[1024]
#define WS_MASK    8192       // int[1024]
#define WS_LACC    12288      // double[256] -> 14336
#define WS_WCNT    14336      // u32 worklist counter
#define WS_WCNT2   14340      // u32 overflow-list counter
#define WS_WSW     16384      // u16[1024*256] swizzled f16 Wn (512 KB)
#define WS_CNT     540672     // u32[65536]
#define WS_CAND    802816     // u16[65536*CAPG] (1 MB) -> 1851392
#define WS_WLIST   1851392    // u32[65536] -> 2113536
#define WS_WLIST2  2113536    // u32[65536] -> 2375680

static __device__ __forceinline__ u32 pk2fh(float a, float b) { // packed f32->f16 RNE
    __half2 p = __float22half2_rn(make_float2(a, b));
    return *reinterpret_cast<u32*>(&p);
}
static __device__ __forceinline__ u32 keyenc(float f) { // monotone f32->u32
    u32 u = __float_as_uint(f);
    return u ^ (u32)(((int)u >> 31) | 0x80000000);
}
static __device__ __forceinline__ float keydec(u32 k) {
    u32 u = (k & 0x80000000u) ? (k ^ 0x80000000u) : ~k;
    return __uint_as_float(u);
}

// --------------------------------------------------------------------------
// K1 prep: norms + f16 normalized W, laid out so each (chunk nb2, kc) B
// slice is one contiguous 16 KB block of B-fragments:
//   Wsw_u16[g(32)][f(16)][lane(64)][j(8)]
//   g = (n>>8)*8 + kc          (kc = 32-dim step within the 256-dim row)
//   f = nq*4 + ni = ((n>>6)&3)*4 + ((n>>4)&3)
//   lane = q*16 + (n&15),  q = (d>>3)&3,  j = d&7
// Zeroes mask/lacc/wcnt/wcnt2 (ws re-poisoned each call).
// --------------------------------------------------------------------------
__global__ void k_prep(const float* __restrict__ W, u16* __restrict__ Wsw,
                       float* __restrict__ inv_norm, float* __restrict__ normW,
                       int* __restrict__ mask, double* __restrict__ lacc,
                       u32* __restrict__ wcnt, u32* __restrict__ wcnt2) {
    const int n = blockIdx.x;      // 1024
    const int l = threadIdx.x;     // 64
    const float4 v = reinterpret_cast<const float4*>(W + (size_t)n * E_DIM)[l];
    float s = v.x * v.x + v.y * v.y + v.z * v.z + v.w * v.w;
#pragma unroll
    for (int sh = 1; sh < 64; sh <<= 1) s += __shfl_xor(s, sh, 64);
    const float nw = sqrtf(s), inv = 1.0f / nw;
    if (l == 0) {
        inv_norm[n] = inv; normW[n] = nw; mask[n] = 0;
        if (n < 256) lacc[n] = 0.0;
        if (n == 0) { *wcnt = 0u; *wcnt2 = 0u; }
    }
    const int o = l >> 1;          // dim-octet 0..31 (dims o*8 .. o*8+7)
    const int kc = o >> 2, q = o & 3;
    const int g  = ((n >> 8) << 3) | kc;
    const int f  = (((n >> 6) & 3) << 2) | ((n >> 4) & 3);
    const size_t base = (((size_t)g * 16 + f) * 64 + (q * 16 + (n & 15))) * 8
                        + (l & 1) * 4;
    u32* dst = reinterpret_cast<u32*>(Wsw + base);
    dst[0] = pk2fh(v.x * inv, v.y * inv);
    dst[1] = pk2fh(v.z * inv, v.w * inv);
}

// --------------------------------------------------------------------------
// K2 score: 128 tokens x 1024 codes, 512 threads = 8 waves
// (2 mq x 4 nq, 4x4 acc/wave). B double-buffered in LDS, staged via
// global_load_lds one kc ahead; one barrier per kc.
// LDS: A 64KB + B 2x16KB + bestk/cnt 1KB + slots 12KB = 109 KB -> 1 blk/CU.
// --------------------------------------------------------------------------
__global__ __launch_bounds__(512, 2)
void k_score(const float* __restrict__ z, const u16* __restrict__ Wsw,
             const float* __restrict__ normW, u16* __restrict__ cand_g,
             u32* __restrict__ cnt_g, int* __restrict__ mask,
             u32* __restrict__ wlist, u32* __restrict__ wcnt,
             u32* __restrict__ wlist2, u32* __restrict__ wcnt2,
             double* __restrict__ lacc) {
    __shared__ __align__(16) u16 A_sw[32768];     // [kc(8)][mt(8)][lane(64)][j(8)]
    __shared__ __align__(16) u16 B_buf[2][8192];  // 2 x 16KB kc-slice of Wsw
    __shared__ u32 bestk[128];
    __shared__ u32 cnt[128];
    __shared__ u32 slots[128 * CAPL];             // (fix16 score<<16) | code

    const int t    = threadIdx.x;
    const int lane = t & 63;
    const int w    = t >> 6;
    const size_t tok_base = (size_t)blockIdx.x * 128;

    if (t < 128) { bestk[t] = 0u; cnt[t] = 0u; }

// stage kc-slice G of Wsw (16 KB) into B_buf[BUF]; per thread 2x16B.
// LDS dest is wave-uniform base + lane*16 (HW rule); global src per-lane.
#define STAGE(BUF, G) { \
    const u16* gsrc = Wsw + (size_t)(G) * 8192 + (size_t)w * 1024 + (size_t)lane * 8; \
    u16* ldst = &B_buf[BUF][w * 1024]; \
    __builtin_amdgcn_global_load_lds( \
        (const __attribute__((address_space(1))) void*)gsrc, \
        (__attribute__((address_space(3))) void*)ldst, 16, 0, 0); \
    __builtin_amdgcn_global_load_lds( \
        (const __attribute__((address_space(1))) void*)(gsrc + 512), \
        (__attribute__((address_space(3))) void*)(ldst + 512), 16, 0, 0); }

    // ---- A staging (l[2:0] -> m&7: conflict-free ds_write) + sum(z^2);
    //      B kc-slice 0 staged concurrently (drained by the same barrier) ----
    STAGE(0, 0);
    float ssq = 0.f;
#pragma unroll
    for (int i = 0; i < 8; i++) {
        const int m = ((i & 1) << 6) | (w << 3) | (lane & 7);    // token row
        const int o = ((i >> 1) << 3) | (lane >> 3);             // k-octet
        const float* zp = z + (tok_base + m) * E_DIM + o * 8;
        const float4 v0 = reinterpret_cast<const float4*>(zp)[0];
        const float4 v1 = reinterpret_cast<const float4*>(zp)[1];
        ssq += v0.x * v0.x + v0.y * v0.y + v0.z * v0.z + v0.w * v0.w
             + v1.x * v1.x + v1.y * v1.y + v1.z * v1.z + v1.w * v1.w;
        uint4 d;
        d.x = pk2fh(v0.x, v0.y);
        d.y = pk2fh(v0.z, v0.w);
        d.z = pk2fh(v1.x, v1.y);
        d.w = pk2fh(v1.z, v1.w);
        const int kc = o >> 2, q = o & 3, col = m & 15, mt = m >> 4;
        *reinterpret_cast<uint4*>(A_sw + ((size_t)((kc * 8 + mt) * 64 + q * 16 + col)) * 8) = d;
    }
#pragma unroll
    for (int sh = 1; sh < 64; sh <<= 1) ssq += __shfl_xor(ssq, sh, 64);
    if (lane == 0) atomicAdd(&lacc[(blockIdx.x * 8 + w) & 255], (double)ssq);
    __syncthreads();   // A ready; B slice 0 drained (vmcnt) and visible

    const int mq = w >> 2;                 // token half (64 tokens, mi=4)
    const int nq = w & 3;                  // code 64-group within chunk (ni=4)
    const int q = lane >> 4, col = lane & 15;

    f32x4 acc[4][4];

#define ZERO_ACC() { _Pragma("unroll") for (int mi = 0; mi < 4; mi++) \
    _Pragma("unroll") for (int ni = 0; ni < 4; ni++) { \
        f32x4 zf = {0.f, 0.f, 0.f, 0.f}; acc[mi][ni] = zf; } }

// max-prescreen: one fused max + compare skips the branchy per-ni admission
// checks (and folds 4 atomicMax into 1) in the common no-admission case.
#define ADMIT(NB2, DO_MAX) { \
    _Pragma("unroll") for (int mi = 0; mi < 4; mi++) \
    _Pragma("unroll") for (int r = 0; r < 4; r++) { \
        const int tk = mq * 64 + mi * 16 + q * 4 + r; \
        const float thr = keydec(bestk[tk]) - D_ADM; \
        const float vmax = fmaxf(fmaxf(acc[mi][0][r], acc[mi][1][r]), \
                                 fmaxf(acc[mi][2][r], acc[mi][3][r])); \
        if (vmax >= thr) { \
            if (DO_MAX) atomicMax(&bestk[tk], keyenc(vmax)); \
            _Pragma("unroll") for (int ni = 0; ni < 4; ni++) { \
                const float v = acc[mi][ni][r]; \
                if (v >= thr) { \
                    const int code = ((NB2) * 16 + nq * 4 + ni) * 16 + col; \
                    const u32 sl = atomicAdd(&cnt[tk], 1u); \
                    if (sl < CAPL) { \
                        const float vc = fminf(fmaxf((v + 16.f) * 2048.f, 0.f), 65535.f); \
                        slots[tk * CAPL + sl] = ((u32)vc << 16) | (u32)code; \
                    } } } } } }

    // ---- main loop: 32 kc-slices (4 chunks x 8 kc), B double-buffered ----
    ZERO_ACC();
    int buf = 0;
#pragma unroll 1
    for (int g = 0; g < 32; ++g) {
        const int nb2 = g >> 3, kc = g & 7;
        if (g < 31) STAGE(buf ^ 1, g + 1);   // prefetch next slice

        f16x8 bf[4], af[4];
#pragma unroll
        for (int ni = 0; ni < 4; ni++)
            bf[ni] = *reinterpret_cast<const f16x8*>(
                &B_buf[buf][((nq * 4 + ni) * 64 + lane) * 8]);
#pragma unroll
        for (int mi = 0; mi < 4; mi++)
            af[mi] = *reinterpret_cast<const f16x8*>(
                A_sw + ((size_t)((kc * 8 + mq * 4 + mi) * 64 + lane)) * 8);
        __builtin_amdgcn_s_setprio(1);
#pragma unroll
        for (int mi = 0; mi < 4; mi++)
#pragma unroll
            for (int ni = 0; ni < 4; ni++)
                acc[mi][ni] = __builtin_amdgcn_mfma_f32_16x16x32_f16(
                    af[mi], bf[ni], acc[mi][ni], 0, 0, 0);
        __builtin_amdgcn_s_setprio(0);

        if (kc == 7) {
            if (nb2 == 0) {
                // tight bestk over chunk 0 (shfl chains + ONE barrier)
#pragma unroll
                for (int mi = 0; mi < 4; mi++)
#pragma unroll
                    for (int r = 0; r < 4; r++) {
                        float m0 = fmaxf(fmaxf(acc[mi][0][r], acc[mi][1][r]),
                                         fmaxf(acc[mi][2][r], acc[mi][3][r]));
#pragma unroll
                        for (int sh = 1; sh < 16; sh <<= 1)
                            m0 = fmaxf(m0, __shfl_xor(m0, sh, 64));
                        if (col == 0)
                            atomicMax(&bestk[mq * 64 + mi * 16 + q * 4 + r], keyenc(m0));
                    }
                __syncthreads();   // bestk now tight over 256 codes
                ADMIT(0, 0);
            } else {
                // stale bestk only loosens admission; true winner always passes
                ADMIT(nb2, 1);
            }
            ZERO_ACC();
        }
        __syncthreads();   // drains stage vmcnt + all B reads; swap safe
        buf ^= 1;
    }
#undef ZERO_ACC
#undef ADMIT
#undef STAGE

    // ---- compaction: m==1 -> finish; 2..CAPG -> wlist; else -> wlist2 ----
    if (t < 128) {
        const size_t tokg = tok_base + t;
        const u32 c = cnt[t];
        const float best = keydec(bestk[t]);
        bool amb = false, ovf = false;
        float xacc = 0.f;
        if (c > CAPL) {
            ovf = true;                                  // rare: full scan
        } else {
            const float thrf = best - D_FIL;
            u16 loc[CAPG]; u32 m = 0;
            for (u32 i = 0; i < c; i++) {
                const u32 s2 = slots[t * CAPL + i];
                const float ap = (float)(s2 >> 16) * (1.0f / 2048.0f) - 16.0f;
                if (ap >= thrf) { if (m < CAPG) loc[m] = (u16)(s2 & 0xFFFFu); m++; }
            }
            if (m == 1) {
                const int bi = loc[0];
                mask[bi] = 1;                            // benign race
                const float nw = normW[bi];
                xacc = fmaf(-2.0f * best, nw, nw * nw);  // -2 z.Wbi + |Wbi|^2
            } else if (m <= CAPG) {
                for (u32 i = 0; i < m; i++) cand_g[tokg * CAPG + i] = loc[i];
                cnt_g[tokg] = m; amb = true;
            } else {
                ovf = true;
            }
        }
        // ambiguous -> wlist
        {
            const u64 bal = __ballot(amb);
            u32 base = 0;
            if (lane == 0 && bal) base = atomicAdd(wcnt, (u32)__popcll(bal));
            base = (u32)__shfl((int)base, 0, 64);
            if (amb) wlist[base + (u32)__popcll(bal & ((1ull << lane) - 1ull))] = (u32)tokg;
        }
        // overflow -> wlist2
        {
            const u64 bal = __ballot(ovf);
            u32 base = 0;
            if (lane == 0 && bal) base = atomicAdd(wcnt2, (u32)__popcll(bal));
            base = (u32)__shfl((int)base, 0, 64);
            if (ovf) wlist2[base + (u32)__popcll(bal & ((1ull << lane) - 1ull))] = (u32)tokg;
        }
        float xs = xacc;
#pragma unroll
        for (int sh = 1; sh < 64; sh <<= 1) xs += __shfl_xor(xs, sh, 64);
        if (lane == 0) atomicAdd(&lacc[(blockIdx.x * 2 + w) & 255], (double)xs);
    }
}

// --------------------------------------------------------------------------
// K3 pick (fused): phase 1 = wlist tokens (sc in [2,CAPG]), 16 lanes/token,
// grid-stride; phase 2 = overflow tokens (rare) block-parallel exact full
// scan (uniform trip count -> internal __syncthreads is safe after the
// divergent phase-1 loop reconverges).
// --------------------------------------------------------------------------
__global__ __launch_bounds__(256)
void k_pick(const float* __restrict__ z, const float* __restrict__ W,
            const float* __restrict__ inv_norm, const float* __restrict__ normW,
            const u16* __restrict__ cand_g, const u32* __restrict__ cnt_g,
            const u32* __restrict__ wlist, const u32* __restrict__ wcnt,
            const u32* __restrict__ wlist2, const u32* __restrict__ wcnt2,
            int* __restrict__ mask, double* __restrict__ lacc) {
    __shared__ float zrow[E_DIM];
    __shared__ float gbv[16], gbp[16];
    __shared__ int   gbi[16];
    const int t = threadIdx.x, lane = t & 63;
    const int gl = t & 15, grp = t >> 4;

    // ---- phase 1: ambiguous tokens ----
    {
        const u32 total = *wcnt;
        float xs = 0.f;
        for (u32 i = blockIdx.x * 16 + grp; i < total; i += 1024 * 16) {
            const size_t tok = wlist[i];
            float4 zv[4];
#pragma unroll
            for (int j = 0; j < 4; j++)
                zv[j] = reinterpret_cast<const float4*>(z + tok * E_DIM)[j * 16 + gl];
            const int n_it = (int)cnt_g[tok];
            float bv = -3.4e38f, bp = 0.f;
            int bi = 0x7FFFFFFF;
#pragma unroll 1
            for (int k2 = 0; k2 < n_it; k2++) {
                const int c = (int)cand_g[tok * CAPG + k2];
                float p = 0.f;
#pragma unroll
                for (int j = 0; j < 4; j++) {
                    const float4 wv = reinterpret_cast<const float4*>(W + (size_t)c * E_DIM)[j * 16 + gl];
                    p += zv[j].x * wv.x + zv[j].y * wv.y + zv[j].z * wv.z + zv[j].w * wv.w;
                }
#pragma unroll
                for (int sh = 1; sh < 16; sh <<= 1) p += __shfl_xor(p, sh, 64);
                const float s = p * inv_norm[c];
                if (s > bv || (s == bv && c < bi)) { bv = s; bi = c; bp = p; }
            }
            if (gl == 0) {
                mask[bi] = 1;
                xs += fmaf(-2.0f, bp, normW[bi] * normW[bi]);
            }
        }
        xs += __shfl_xor(xs, 16, 64);
        xs += __shfl_xor(xs, 32, 64);
        if (lane == 0) atomicAdd(&lacc[(blockIdx.x * 4 + (t >> 6)) & 255], (double)xs);
    }

    // ---- phase 2: overflow tokens -- block-parallel exact full scan.
    // 16 groups x 64 codes each (2 codes in flight), LDS merge with
    // ascending-index ties. Trip count uniform across the block.
    {
        const u32 total2 = *wcnt2;
        for (u32 i = blockIdx.x; i < total2; i += 1024) {
            const size_t tok = wlist2[i];
            __syncthreads();              // protect zrow reuse / phase boundary
            zrow[t] = z[tok * E_DIM + t];
            __syncthreads();
            float4 zv[4];
#pragma unroll
            for (int j = 0; j < 4; j++)
                zv[j] = reinterpret_cast<const float4*>(zrow)[j * 16 + gl];
            float bv = -3.4e38f, bp = 0.f;
            int bi = 0x7FFFFFFF;
#pragma unroll 1
            for (int k2 = 0; k2 < 64; k2 += 2) {
                const int c0 = grp * 64 + k2, c1 = c0 + 1;
                float p0 = 0.f, p1 = 0.f;
#pragma unroll
                for (int j = 0; j < 4; j++) {
                    const float4 w0 = reinterpret_cast<const float4*>(W + (size_t)c0 * E_DIM)[j * 16 + gl];
                    const float4 w1 = reinterpret_cast<const float4*>(W + (size_t)c1 * E_DIM)[j * 16 + gl];
                    p0 += zv[j].x * w0.x + zv[j].y * w0.y + zv[j].z * w0.z + zv[j].w * w0.w;
                    p1 += zv[j].x * w1.x + zv[j].y * w1.y + zv[j].z * w1.z + zv[j].w * w1.w;
                }
#pragma unroll
                for (int sh = 1; sh < 16; sh <<= 1) {
                    p0 += __shfl_xor(p0, sh, 64);
                    p1 += __shfl_xor(p1, sh, 64);
                }
                const float s0 = p0 * inv_norm[c0];
                const float s1 = p1 * inv_norm[c1];
                if (s0 > bv || (s0 == bv && c0 < bi)) { bv = s0; bi = c0; bp = p0; }
                if (s1 > bv || (s1 == bv && c1 < bi)) { bv = s1; bi = c1; bp = p1; }
            }
            if (gl == 0) { gbv[grp] = bv; gbi[grp] = bi; gbp[grp] = bp; }
            __syncthreads();
            if (t == 0) {
                float fb = gbv[0], fp = gbp[0];
                int fi = gbi[0];
                for (int g2 = 1; g2 < 16; g2++) {
                    const float v2 = gbv[g2];
                    const int i2 = gbi[g2];
                    if (v2 > fb || (v2 == fb && i2 < fi)) { fb = v2; fi = i2; fp = gbp[g2]; }
                }
                mask[fi] = 1;
                atomicAdd(&lacc[tok & 255],
                          (double)fmaf(-2.0f, fp, normW[fi] * normW[fi]));
            }
        }
    }
}

// --------------------------------------------------------------------------
// K4 emit (fused rank): each block redundantly reduces mask for prefix(e)
// and total; writes emb row + label. Block 0 finalizes loss.
// --------------------------------------------------------------------------
__global__ __launch_bounds__(256)
void k_emit(const float* __restrict__ W, const int* __restrict__ mask,
            const double* __restrict__ lacc, float* __restrict__ out) {
    __shared__ int    redp[256], redt[256];
    __shared__ double dred[256];
    const int e = blockIdx.x;              // 1024
    const int t = threadIdx.x;             // 256
    const int4 mv = reinterpret_cast<const int4*>(mask)[t];
    const int b = t * 4;
    redt[t] = mv.x + mv.y + mv.z + mv.w;
    redp[t] = (b + 0 < e ? mv.x : 0) + (b + 1 < e ? mv.y : 0) +
              (b + 2 < e ? mv.z : 0) + (b + 3 < e ? mv.w : 0);
    if (e == 0) dred[t] = lacc[t];
    __syncthreads();
#pragma unroll
    for (int s2 = 128; s2 > 0; s2 >>= 1) {
        if (t < s2) {
            redp[t] += redp[t + s2];
            redt[t] += redt[t + s2];
            if (e == 0) dred[t] += dred[t + s2];
        }
        __syncthreads();
    }
    const int prefix = redp[0], total = redt[0];
    const int m = mask[e];
    const int r = m ? prefix : (total + e - prefix);
    out[(size_t)r * E_DIM + t] = W[(size_t)e * E_DIM + t];
    if (t == 0) out[(size_t)N_E * E_DIM + r] = m ? 1.0f : 0.0f;
    if (e == 0 && t == 0) {
        const double mse = dred[0] / (double)((size_t)N_TOK * E_DIM);
        out[(size_t)N_E * E_DIM + N_E] = (float)((1.0 + (double)BETA) * mse);
    }
}

// --------------------------------------------------------------------------
extern "C" void kernel_launch(void* const* d_in, const int* in_sizes, int n_in,
                              void* d_out, int out_size, void* d_ws, size_t ws_size,
                              hipStream_t stream) {
    const float* z = (const float*)d_in[0];
    const float* W = (const float*)d_in[1];
    float* out = (float*)d_out;
    char* ws = (char*)d_ws;

    float*  inv_norm = (float*)(ws + WS_INVNORM);
    float*  normW    = (float*)(ws + WS_NORMW);
    int*    mask     = (int*)(ws + WS_MASK);
    double* lacc     = (double*)(ws + WS_LACC);
    u32*    wcnt     = (u32*)(ws + WS_WCNT);
    u32*    wcnt2    = (u32*)(ws + WS_WCNT2);
    u16*    Wsw      = (u16*)(ws + WS_WSW);
    u32*    cnt      = (u32*)(ws + WS_CNT);
    u16*    cand     = (u16*)(ws + WS_CAND);
    u32*    wlist    = (u32*)(ws + WS_WLIST);
    u32*    wlist2   = (u32*)(ws + WS_WLIST2);

    k_prep <<<N_E, 64, 0, stream>>>(W, Wsw, inv_norm, normW, mask, lacc,
                                    wcnt, wcnt2);
    k_score<<<N_TOK / 128, 512, 0, stream>>>(z, Wsw, normW, cand, cnt, mask,
                                             wlist, wcnt, wlist2, wcnt2, lacc);
    k_pick <<<1024, 256, 0, stream>>>(z, W, inv_norm, normW, cand, cnt,
                                      wlist, wcnt, wlist2, wcnt2, mask, lacc);
    k_emit <<<N_E, 256, 0, stream>>>(W, mask, lacc, out);
}

// Round 8
// 182.702 us; speedup vs baseline: 1.0249x; 1.0091x over previous
//
#include <hip/hip_runtime.h>
#include <hip/hip_bf16.h>
#include <hip/hip_fp16.h>
#include <math.h>

// ---------------------------------------------------------------------------
// TaggingQuantizer: cosine-distance VQ assignment + loss + pos/neg reorder.
//   z: (65536, 256) f32,  W: (1024, 256) f32
//   out: emb (1024*256) | label (1024) | loss (1)   all f32, flat-concat.
//
// k_score: f16 MFMA screen (16x16x32), chunk0-tight bestk (one barrier) then
// barrier-free streaming chunks. Unique survivors finish via the loss
// identity. Ambiguous (2..CAPG) -> wlist -> k_pick. Overflow (rare) ->
// wlist2 -> phase 2 of k_pick (block-parallel full scan).
//
// R17: REVERT to R12 (best known: k_score 65us, total 150.5) + explicit
//      software-pipelined B path. R16 (B via LDS) was LDS-BW-doomed
//      (A-reads already ~750cyc/kc; +B pushed LDS past MFMA) and 1 blk/CU
//      exposed every barrier drain. B stays on L2->register path.
//      Change: ping-pong bfA/bfB; kc+1's 4 B-loads issued BEFORE kc's
//      MFMAs (program order, so the compiler need not hoist); next chunk's
//      first B-loads issued BEFORE ADMIT (chunks 1-3 are barrier-free, so
//      they stay in flight while admission VALU runs). Register budget:
//      acc 64 AGPR + bfA/bfB 32 + af 16 + addr ~10 <= 128 total keeps
//      2 blocks/CU under __launch_bounds__(512,4) (fail-safe: if the
//      allocator sinks the prefetch we land back at R12 perf).
// ---------------------------------------------------------------------------

typedef unsigned short u16;
typedef unsigned int   u32;
typedef unsigned long long u64;
typedef __attribute__((ext_vector_type(8))) _Float16 f16x8; // 8 f16 (4 VGPR)
typedef __attribute__((ext_vector_type(4))) float f32x4;

#define N_E   1024
#define E_DIM 256
#define N_TOK 65536
#define BETA  0.25f
#define CAPL  24      // LDS slots/token
#define CAPG  8       // global candidates/token
#define D_ADM 0.025f  // admission margin (> 2*E_wc, E_wc <= ||z||*2^-11 = 0.0093)
#define D_FIL 0.026f  // final filter: D_ADM + fix16 trunc (4.9e-4) + slack

// ws layout (bytes)
#define WS_INVNORM 0          // float[1024]
#define WS_NORMW   4096       // float[1024]
#define WS_MASK    8192       // int[1024]
#define WS_LACC    12288      // double[256] -> 14336
#define WS_WCNT    14336      // u32 worklist counter
#define WS_WCNT2   14340      // u32 overflow-list counter
#define WS_WSW     16384      // u16[1024*256] swizzled f16 Wn (512 KB)
#define WS_CNT     540672     // u32[65536]
#define WS_CAND    802816     // u16[65536*CAPG] (1 MB) -> 1851392
#define WS_WLIST   1851392    // u32[65536] -> 2113536
#define WS_WLIST2  2113536    // u32[65536] -> 2375680

static __device__ __forceinline__ u32 pk2fh(float a, float b) { // packed f32->f16 RNE
    __half2 p = __float22half2_rn(make_float2(a, b));
    return *reinterpret_cast<u32*>(&p);
}
static __device__ __forceinline__ u32 keyenc(float f) { // monotone f32->u32
    u32 u = __float_as_uint(f);
    return u ^ (u32)(((int)u >> 31) | 0x80000000);
}
static __device__ __forceinline__ float keydec(u32 k) {
    u32 u = (k & 0x80000000u) ? (k ^ 0x80000000u) : ~k;
    return __uint_as_float(u);
}

// --------------------------------------------------------------------------
// K1 prep: norms + swizzled f16 normalized W in MFMA B-fragment order.
// Zeroes mask/lacc/wcnt/wcnt2 (ws re-poisoned each call).
// --------------------------------------------------------------------------
__global__ void k_prep(const float* __restrict__ W, u16* __restrict__ Wsw,
                       float* __restrict__ inv_norm, float* __restrict__ normW,
                       int* __restrict__ mask, double* __restrict__ lacc,
                       u32* __restrict__ wcnt, u32* __restrict__ wcnt2) {
    const int n = blockIdx.x;      // 1024
    const int l = threadIdx.x;     // 64
    const float4 v = reinterpret_cast<const float4*>(W + (size_t)n * E_DIM)[l];
    float s = v.x * v.x + v.y * v.y + v.z * v.z + v.w * v.w;
#pragma unroll
    for (int sh = 1; sh < 64; sh <<= 1) s += __shfl_xor(s, sh, 64);
    const float nw = sqrtf(s), inv = 1.0f / nw;
    if (l == 0) {
        inv_norm[n] = inv; normW[n] = nw; mask[n] = 0;
        if (n < 256) lacc[n] = 0.0;
        if (n == 0) { *wcnt = 0u; *wcnt2 = 0u; }
    }
    const int o = l >> 1;          // k-octet 0..31
    const int kc = o >> 2, q = o & 3;
    const size_t base =
        (((((size_t)(n >> 7) * 8 + kc) * 8 + ((n >> 4) & 7)) * 64 +
          (q * 16 + (n & 15))) * 8) + (l & 1) * 4;
    u32* dst = reinterpret_cast<u32*>(Wsw + base);
    dst[0] = pk2fh(v.x * inv, v.y * inv);
    dst[1] = pk2fh(v.z * inv, v.w * inv);
}

// --------------------------------------------------------------------------
// K2 score: 128 tokens x 1024 codes, 512 threads = 8 waves
// (2 mq x 4 nq, 4x4 acc/wave over 256-code chunks). One barrier after
// chunk 0 (tight bestk); chunks 1-3 stream barrier-free.
// LDS: A 64KB + bestk/cnt 1KB + slots 12KB = 78.8 KB -> 2 blocks/CU.
// B path software-pipelined: ping-pong bfA/bfB, loads one kc ahead,
// cross-chunk prefetch in flight through ADMIT.
// --------------------------------------------------------------------------
__global__ __launch_bounds__(512, 4)
void k_score(const float* __restrict__ z, const u16* __restrict__ Wsw,
             const float* __restrict__ normW, u16* __restrict__ cand_g,
             u32* __restrict__ cnt_g, int* __restrict__ mask,
             u32* __restrict__ wlist, u32* __restrict__ wcnt,
             u32* __restrict__ wlist2, u32* __restrict__ wcnt2,
             double* __restrict__ lacc) {
    __shared__ __align__(16) u16 A_sw[32768];   // [kc(8)][mt(8)][lane(64)][j(8)]
    __shared__ u32 bestk[128];
    __shared__ u32 cnt[128];
    __shared__ u32 slots[128 * CAPL];           // (fix16 score<<16) | code

    const int t    = threadIdx.x;
    const int lane = t & 63;
    const int w    = t >> 6;
    const size_t tok_base = (size_t)blockIdx.x * 128;

    if (t < 128) { bestk[t] = 0u; cnt[t] = 0u; }

    // ---- staging (l[2:0] -> m&7: conflict-free ds_write) + fused sum(z^2) --
    float ssq = 0.f;
#pragma unroll
    for (int i = 0; i < 8; i++) {
        const int m = ((i & 1) << 6) | (w << 3) | (lane & 7);    // token row
        const int o = ((i >> 1) << 3) | (lane >> 3);             // k-octet
        const float* zp = z + (tok_base + m) * E_DIM + o * 8;
        const float4 v0 = reinterpret_cast<const float4*>(zp)[0];
        const float4 v1 = reinterpret_cast<const float4*>(zp)[1];
        ssq += v0.x * v0.x + v0.y * v0.y + v0.z * v0.z + v0.w * v0.w
             + v1.x * v1.x + v1.y * v1.y + v1.z * v1.z + v1.w * v1.w;
        uint4 d;
        d.x = pk2fh(v0.x, v0.y);
        d.y = pk2fh(v0.z, v0.w);
        d.z = pk2fh(v1.x, v1.y);
        d.w = pk2fh(v1.z, v1.w);
        const int kc = o >> 2, q = o & 3, col = m & 15, mt = m >> 4;
        *reinterpret_cast<uint4*>(A_sw + ((size_t)((kc * 8 + mt) * 64 + q * 16 + col)) * 8) = d;
    }
#pragma unroll
    for (int sh = 1; sh < 64; sh <<= 1) ssq += __shfl_xor(ssq, sh, 64);
    if (lane == 0) atomicAdd(&lacc[(blockIdx.x * 8 + w) & 255], (double)ssq);
    __syncthreads();

    const int mq = w >> 2;                 // token half (64 tokens, mi=4)
    const int nq = w & 3;                  // code 64-group within chunk (ni=4)
    const int q = lane >> 4, col = lane & 15;
    const u16* wb = Wsw + ((size_t)((nq >> 1) * 64 + (nq & 1) * 4)) * 512
                        + (size_t)lane * 8;

    f32x4 acc[4][4];
    f16x8 bfA[4], bfB[4];   // ping-pong B fragments (prefetch depth 1)

#define ZERO_ACC() { _Pragma("unroll") for (int mi = 0; mi < 4; mi++) \
    _Pragma("unroll") for (int ni = 0; ni < 4; ni++) { \
        f32x4 zf = {0.f, 0.f, 0.f, 0.f}; acc[mi][ni] = zf; } }

// load the 4 B fragments of slice SL (= nb2*16 + kc) into DST
#define LOADB(DST, SL) { _Pragma("unroll") for (int ni = 0; ni < 4; ni++) \
    (DST)[ni] = *reinterpret_cast<const f16x8*>( \
        wb + (size_t)((SL) * 8 + ni) * 512); }

// A-reads + 16 MFMA for kc KC using B fragments CUR
#define MSTEP(KC, CUR) { \
    f16x8 af[4]; \
    _Pragma("unroll") for (int mi = 0; mi < 4; mi++) \
        af[mi] = *reinterpret_cast<const f16x8*>( \
            A_sw + ((size_t)(((KC) * 8 + mq * 4 + mi) * 64 + lane)) * 8); \
    __builtin_amdgcn_s_setprio(1); \
    _Pragma("unroll") for (int mi = 0; mi < 4; mi++) \
    _Pragma("unroll") for (int ni = 0; ni < 4; ni++) \
        acc[mi][ni] = __builtin_amdgcn_mfma_f32_16x16x32_f16( \
            af[mi], (CUR)[ni], acc[mi][ni], 0, 0, 0); \
    __builtin_amdgcn_s_setprio(0); }

// max-prescreen: one fused max + compare skips the branchy per-ni admission
// checks (and folds 4 atomicMax into 1) in the common no-admission case.
#define ADMIT(NB2, DO_MAX) { \
    _Pragma("unroll") for (int mi = 0; mi < 4; mi++) \
    _Pragma("unroll") for (int r = 0; r < 4; r++) { \
        const int tk = mq * 64 + mi * 16 + q * 4 + r; \
        const float thr = keydec(bestk[tk]) - D_ADM; \
        const float vmax = fmaxf(fmaxf(acc[mi][0][r], acc[mi][1][r]), \
                                 fmaxf(acc[mi][2][r], acc[mi][3][r])); \
        if (vmax >= thr) { \
            if (DO_MAX) atomicMax(&bestk[tk], keyenc(vmax)); \
            _Pragma("unroll") for (int ni = 0; ni < 4; ni++) { \
                const float v = acc[mi][ni][r]; \
                if (v >= thr) { \
                    const int code = ((NB2) * 16 + nq * 4 + ni) * 16 + col; \
                    const u32 sl = atomicAdd(&cnt[tk], 1u); \
                    if (sl < CAPL) { \
                        const float vc = fminf(fmaxf((v + 16.f) * 2048.f, 0.f), 65535.f); \
                        slots[tk * CAPL + sl] = ((u32)vc << 16) | (u32)code; \
                    } } } } } }

    // ---- pipelined main loop: 4 chunks x 8 kc; B loads one kc ahead ----
    LOADB(bfA, 0);   // prologue (post-barrier: keeps staging-phase VGPR peak)
#pragma unroll 1
    for (int nb2 = 0; nb2 < 4; nb2++) {
        ZERO_ACC();
#pragma unroll
        for (int kp = 0; kp < 4; kp++) {
            const int k0 = kp * 2, k1 = k0 + 1;
            LOADB(bfB, nb2 * 16 + k1);            // prefetch odd kc
            MSTEP(k0, bfA);
            if (k1 < 7) {
                LOADB(bfA, nb2 * 16 + k1 + 1);    // prefetch next even kc
            } else if (nb2 < 3) {
                LOADB(bfA, (nb2 + 1) * 16);       // next chunk's kc0: stays in
            }                                     // flight through ADMIT below
            MSTEP(k1, bfB);
        }
        if (nb2 == 0) {
            // tight bestk over chunk 0 (shfl chains + ONE barrier)
#pragma unroll
            for (int mi = 0; mi < 4; mi++)
#pragma unroll
                for (int r = 0; r < 4; r++) {
                    float m0 = fmaxf(fmaxf(acc[mi][0][r], acc[mi][1][r]),
                                     fmaxf(acc[mi][2][r], acc[mi][3][r]));
#pragma unroll
                    for (int sh = 1; sh < 16; sh <<= 1)
                        m0 = fmaxf(m0, __shfl_xor(m0, sh, 64));
                    if (col == 0)
                        atomicMax(&bestk[mq * 64 + mi * 16 + q * 4 + r], keyenc(m0));
                }
            __syncthreads();   // bestk now tight over 256 codes
            ADMIT(0, 0);
        } else {
            // stale bestk only loosens admission; true winner always passes
            ADMIT(nb2, 1);
        }
    }
#undef ZERO_ACC
#undef LOADB
#undef MSTEP
#undef ADMIT

    __syncthreads();
    // ---- compaction: m==1 -> finish; 2..CAPG -> wlist; else -> wlist2 ----
    if (t < 128) {
        const size_t tokg = tok_base + t;
        const u32 c = cnt[t];
        const float best = keydec(bestk[t]);
        bool amb = false, ovf = false;
        float xacc = 0.f;
        if (c > CAPL) {
            ovf = true;                                  // rare: full scan
        } else {
            const float thrf = best - D_FIL;
            u16 loc[CAPG]; u32 m = 0;
            for (u32 i = 0; i < c; i++) {
                const u32 s2 = slots[t * CAPL + i];
                const float ap = (float)(s2 >> 16) * (1.0f / 2048.0f) - 16.0f;
                if (ap >= thrf) { if (m < CAPG) loc[m] = (u16)(s2 & 0xFFFFu); m++; }
            }
            if (m == 1) {
                const int bi = loc[0];
                mask[bi] = 1;                            // benign race
                const float nw = normW[bi];
                xacc = fmaf(-2.0f * best, nw, nw * nw);  // -2 z.Wbi + |Wbi|^2
            } else if (m <= CAPG) {
                for (u32 i = 0; i < m; i++) cand_g[tokg * CAPG + i] = loc[i];
                cnt_g[tokg] = m; amb = true;
            } else {
                ovf = true;
            }
        }
        // ambiguous -> wlist
        {
            const u64 bal = __ballot(amb);
            u32 base = 0;
            if (lane == 0 && bal) base = atomicAdd(wcnt, (u32)__popcll(bal));
            base = (u32)__shfl((int)base, 0, 64);
            if (amb) wlist[base + (u32)__popcll(bal & ((1ull << lane) - 1ull))] = (u32)tokg;
        }
        // overflow -> wlist2
        {
            const u64 bal = __ballot(ovf);
            u32 base = 0;
            if (lane == 0 && bal) base = atomicAdd(wcnt2, (u32)__popcll(bal));
            base = (u32)__shfl((int)base, 0, 64);
            if (ovf) wlist2[base + (u32)__popcll(bal & ((1ull << lane) - 1ull))] = (u32)tokg;
        }
        float xs = xacc;
#pragma unroll
        for (int sh = 1; sh < 64; sh <<= 1) xs += __shfl_xor(xs, sh, 64);
        if (lane == 0) atomicAdd(&lacc[(blockIdx.x * 2 + w) & 255], (double)xs);
    }
}

// --------------------------------------------------------------------------
// K3 pick (fused): phase 1 = wlist tokens (sc in [2,CAPG]), 16 lanes/token,
// grid-stride; phase 2 = overflow tokens (rare) block-parallel exact full
// scan (uniform trip count -> internal __syncthreads is safe after the
// divergent phase-1 loop reconverges).
// --------------------------------------------------------------------------
__global__ __launch_bounds__(256)
void k_pick(const float* __restrict__ z, const float* __restrict__ W,
            const float* __restrict__ inv_norm, const float* __restrict__ normW,
            const u16* __restrict__ cand_g, const u32* __restrict__ cnt_g,
            const u32* __restrict__ wlist, const u32* __restrict__ wcnt,
            const u32* __restrict__ wlist2, const u32* __restrict__ wcnt2,
            int* __restrict__ mask, double* __restrict__ lacc) {
    __shared__ float zrow[E_DIM];
    __shared__ float gbv[16], gbp[16];
    __shared__ int   gbi[16];
    const int t = threadIdx.x, lane = t & 63;
    const int gl = t & 15, grp = t >> 4;

    // ---- phase 1: ambiguous tokens ----
    {
        const u32 total = *wcnt;
        float xs = 0.f;
        for (u32 i = blockIdx.x * 16 + grp; i < total; i += 1024 * 16) {
            const size_t tok = wlist[i];
            float4 zv[4];
#pragma unroll
            for (int j = 0; j < 4; j++)
                zv[j] = reinterpret_cast<const float4*>(z + tok * E_DIM)[j * 16 + gl];
            const int n_it = (int)cnt_g[tok];
            float bv = -3.4e38f, bp = 0.f;
            int bi = 0x7FFFFFFF;
#pragma unroll 1
            for (int k2 = 0; k2 < n_it; k2++) {
                const int c = (int)cand_g[tok * CAPG + k2];
                float p = 0.f;
#pragma unroll
                for (int j = 0; j < 4; j++) {
                    const float4 wv = reinterpret_cast<const float4*>(W + (size_t)c * E_DIM)[j * 16 + gl];
                    p += zv[j].x * wv.x + zv[j].y * wv.y + zv[j].z * wv.z + zv[j].w * wv.w;
                }
#pragma unroll
                for (int sh = 1; sh < 16; sh <<= 1) p += __shfl_xor(p, sh, 64);
                const float s = p * inv_norm[c];
                if (s > bv || (s == bv && c < bi)) { bv = s; bi = c; bp = p; }
            }
            if (gl == 0) {
                mask[bi] = 1;
                xs += fmaf(-2.0f, bp, normW[bi] * normW[bi]);
            }
        }
        xs += __shfl_xor(xs, 16, 64);
        xs += __shfl_xor(xs, 32, 64);
        if (lane == 0) atomicAdd(&lacc[(blockIdx.x * 4 + (t >> 6)) & 255], (double)xs);
    }

    // ---- phase 2: overflow tokens -- block-parallel exact full scan.
    // 16 groups x 64 codes each (2 codes in flight), LDS merge with
    // ascending-index ties. Trip count uniform across the block.
    {
        const u32 total2 = *wcnt2;
        for (u32 i = blockIdx.x; i < total2; i += 1024) {
            const size_t tok = wlist2[i];
            __syncthreads();              // protect zrow reuse / phase boundary
            zrow[t] = z[tok * E_DIM + t];
            __syncthreads();
            float4 zv[4];
#pragma unroll
            for (int j = 0; j < 4; j++)
                zv[j] = reinterpret_cast<const float4*>(zrow)[j * 16 + gl];
            float bv = -3.4e38f, bp = 0.f;
            int bi = 0x7FFFFFFF;
#pragma unroll 1
            for (int k2 = 0; k2 < 64; k2 += 2) {
                const int c0 = grp * 64 + k2, c1 = c0 + 1;
                float p0 = 0.f, p1 = 0.f;
#pragma unroll
                for (int j = 0; j < 4; j++) {
                    const float4 w0 = reinterpret_cast<const float4*>(W + (size_t)c0 * E_DIM)[j * 16 + gl];
                    const float4 w1 = reinterpret_cast<const float4*>(W + (size_t)c1 * E_DIM)[j * 16 + gl];
                    p0 += zv[j].x * w0.x + zv[j].y * w0.y + zv[j].z * w0.z + zv[j].w * w0.w;
                    p1 += zv[j].x * w1.x + zv[j].y * w1.y + zv[j].z * w1.z + zv[j].w * w1.w;
                }
#pragma unroll
                for (int sh = 1; sh < 16; sh <<= 1) {
                    p0 += __shfl_xor(p0, sh, 64);
                    p1 += __shfl_xor(p1, sh, 64);
                }
                const float s0 = p0 * inv_norm[c0];
                const float s1 = p1 * inv_norm[c1];
                if (s0 > bv || (s0 == bv && c0 < bi)) { bv = s0; bi = c0; bp = p0; }
                if (s1 > bv || (s1 == bv && c1 < bi)) { bv = s1; bi = c1; bp = p1; }
            }
            if (gl == 0) { gbv[grp] = bv; gbi[grp] = bi; gbp[grp] = bp; }
            __syncthreads();
            if (t == 0) {
                float fb = gbv[0], fp = gbp[0];
                int fi = gbi[0];
                for (int g2 = 1; g2 < 16; g2++) {
                    const float v2 = gbv[g2];
                    const int i2 = gbi[g2];
                    if (v2 > fb || (v2 == fb && i2 < fi)) { fb = v2; fi = i2; fp = gbp[g2]; }
                }
                mask[fi] = 1;
                atomicAdd(&lacc[tok & 255],
                          (double)fmaf(-2.0f, fp, normW[fi] * normW[fi]));
            }
        }
    }
}

// --------------------------------------------------------------------------
// K4 emit (fused rank): each block redundantly reduces mask for prefix(e)
// and total; writes emb row + label. Block 0 finalizes loss.
// --------------------------------------------------------------------------
__global__ __launch_bounds__(256)
void k_emit(const float* __restrict__ W, const int* __restrict__ mask,
            const double* __restrict__ lacc, float* __restrict__ out) {
    __shared__ int    redp[256], redt[256];
    __shared__ double dred[256];
    const int e = blockIdx.x;              // 1024
    const int t = threadIdx.x;             // 256
    const int4 mv = reinterpret_cast<const int4*>(mask)[t];
    const int b = t * 4;
    redt[t] = mv.x + mv.y + mv.z + mv.w;
    redp[t] = (b + 0 < e ? mv.x : 0) + (b + 1 < e ? mv.y : 0) +
              (b + 2 < e ? mv.z : 0) + (b + 3 < e ? mv.w : 0);
    if (e == 0) dred[t] = lacc[t];
    __syncthreads();
#pragma unroll
    for (int s2 = 128; s2 > 0; s2 >>= 1) {
        if (t < s2) {
            redp[t] += redp[t + s2];
            redt[t] += redt[t + s2];
            if (e == 0) dred[t] += dred[t + s2];
        }
        __syncthreads();
    }
    const int prefix = redp[0], total = redt[0];
    const int m = mask[e];
    const int r = m ? prefix : (total + e - prefix);
    out[(size_t)r * E_DIM + t] = W[(size_t)e * E_DIM + t];
    if (t == 0) out[(size_t)N_E * E_DIM + r] = m ? 1.0f : 0.0f;
    if (e == 0 && t == 0) {
        const double mse = dred[0] / (double)((size_t)N_TOK * E_DIM);
        out[(size_t)N_E * E_DIM + N_E] = (float)((1.0 + (double)BETA) * mse);
    }
}

// --------------------------------------------------------------------------
extern "C" void kernel_launch(void* const* d_in, const int* in_sizes, int n_in,
                              void* d_out, int out_size, void* d_ws, size_t ws_size,
                              hipStream_t stream) {
    const float* z = (const float*)d_in[0];
    const float* W = (const float*)d_in[1];
    float* out = (float*)d_out;
    char* ws = (char*)d_ws;

    float*  inv_norm = (float*)(ws + WS_INVNORM);
    float*  normW    = (float*)(ws + WS_NORMW);
    int*    mask     = (int*)(ws + WS_MASK);
    double* lacc     = (double*)(ws + WS_LACC);
    u32*    wcnt     = (u32*)(ws + WS_WCNT);
    u32*    wcnt2    = (u32*)(ws + WS_WCNT2);
    u16*    Wsw      = (u16*)(ws + WS_WSW);
    u32*    cnt      = (u32*)(ws + WS_CNT);
    u16*    cand     = (u16*)(ws + WS_CAND);
    u32*    wlist    = (u32*)(ws + WS_WLIST);
    u32*    wlist2   = (u32*)(ws + WS_WLIST2);

    k_prep <<<N_E, 64, 0, stream>>>(W, Wsw, inv_norm, normW, mask, lacc,
                                    wcnt, wcnt2);
    k_score<<<N_TOK / 128, 512, 0, stream>>>(z, Wsw, normW, cand, cnt, mask,
                                             wlist, wcnt, wlist2, wcnt2, lacc);
    k_pick <<<1024, 256, 0, stream>>>(z, W, inv_norm, normW, cand, cnt,
                                      wlist, wcnt, wlist2, wcnt2, mask, lacc);
    k_emit <<<N_E, 256, 0, stream>>>(W, mask, lacc, out);
}

// Round 9
// 139.332 us; speedup vs baseline: 1.3439x; 1.3113x over previous
//
#include <hip/hip_runtime.h>
#include <hip/hip_bf16.h>
#include <hip/hip_fp16.h>
#include <math.h>

// ---------------------------------------------------------------------------
// TaggingQuantizer: cosine-distance VQ assignment + loss + pos/neg reorder.
//   z: (65536, 256) f32,  W: (1024, 256) f32
//   out: emb (1024*256) | label (1024) | loss (1)   all f32, flat-concat.
//
// R18: 3-kernel pipeline. Core k_score = exact R12 (best known: 150.5us
//      total). k_pick ELIMINATED: ambiguous tokens are block-local, so a
//      short in-block tail resolves them (32x 16-lane groups, exact f32
//      rescore, op-order identical to the old k_pick); rare overflow gets
//      a block-wide exact full scan. Deletes one dispatch + launch gap +
//      all cand_g/wlist/wcnt global traffic.
//      History: R16 (B via LDS) = LDS-BW bound; R17 (reg ping-pong) =
//      scratch spills (WRITE_SIZE 95MB). B-path register pipelining is
//      falsified both ways under the 64-AGPR acc + 128-reg cap; R12 core
//      kept as-is.
// ---------------------------------------------------------------------------

typedef unsigned short u16;
typedef unsigned int   u32;
typedef unsigned long long u64;
typedef __attribute__((ext_vector_type(8))) _Float16 f16x8; // 8 f16 (4 VGPR)
typedef __attribute__((ext_vector_type(4))) float f32x4;

#define N_E   1024
#define E_DIM 256
#define N_TOK 65536
#define BETA  0.25f
#define CAPL  24      // LDS slots/token
#define CAPG  8       // candidates/token kept for in-block rescore
#define D_ADM 0.025f  // admission margin (> 2*E_wc, E_wc <= ||z||*2^-11 = 0.0093)
#define D_FIL 0.026f  // final filter: D_ADM + fix16 trunc (4.9e-4) + slack

// ws layout (bytes) -- only the first five arrays are used now
#define WS_INVNORM 0          // float[1024]
#define WS_NORMW   4096       // float[1024]
#define WS_MASK    8192       // int[1024]
#define WS_LACC    12288      // double[256] -> 14336
#define WS_WSW     16384      // u16[1024*256] swizzled f16 Wn (512 KB)

static __device__ __forceinline__ u32 pk2fh(float a, float b) { // packed f32->f16 RNE
    __half2 p = __float22half2_rn(make_float2(a, b));
    return *reinterpret_cast<u32*>(&p);
}
static __device__ __forceinline__ u32 keyenc(float f) { // monotone f32->u32
    u32 u = __float_as_uint(f);
    return u ^ (u32)(((int)u >> 31) | 0x80000000);
}
static __device__ __forceinline__ float keydec(u32 k) {
    u32 u = (k & 0x80000000u) ? (k ^ 0x80000000u) : ~k;
    return __uint_as_float(u);
}

// --------------------------------------------------------------------------
// K1 prep: norms + swizzled f16 normalized W in MFMA B-fragment order.
// Zeroes mask/lacc (ws re-poisoned each call).
// --------------------------------------------------------------------------
__global__ void k_prep(const float* __restrict__ W, u16* __restrict__ Wsw,
                       float* __restrict__ inv_norm, float* __restrict__ normW,
                       int* __restrict__ mask, double* __restrict__ lacc) {
    const int n = blockIdx.x;      // 1024
    const int l = threadIdx.x;     // 64
    const float4 v = reinterpret_cast<const float4*>(W + (size_t)n * E_DIM)[l];
    float s = v.x * v.x + v.y * v.y + v.z * v.z + v.w * v.w;
#pragma unroll
    for (int sh = 1; sh < 64; sh <<= 1) s += __shfl_xor(s, sh, 64);
    const float nw = sqrtf(s), inv = 1.0f / nw;
    if (l == 0) {
        inv_norm[n] = inv; normW[n] = nw; mask[n] = 0;
        if (n < 256) lacc[n] = 0.0;
    }
    const int o = l >> 1;          // k-octet 0..31
    const int kc = o >> 2, q = o & 3;
    const size_t base =
        (((((size_t)(n >> 7) * 8 + kc) * 8 + ((n >> 4) & 7)) * 64 +
          (q * 16 + (n & 15))) * 8) + (l & 1) * 4;
    u32* dst = reinterpret_cast<u32*>(Wsw + base);
    dst[0] = pk2fh(v.x * inv, v.y * inv);
    dst[1] = pk2fh(v.z * inv, v.w * inv);
}

// --------------------------------------------------------------------------
// K2 score: 128 tokens x 1024 codes, 512 threads = 8 waves
// (2 mq x 4 nq, 4x4 acc/wave over 256-code chunks). One barrier after
// chunk 0 (tight bestk); chunks 1-3 stream barrier-free. Tail resolves
// ambiguous/overflow tokens in-block (exact f32, k_pick-identical order).
// LDS: A 64KB + bestk/cnt 1KB + slots 12KB + resolver ~1.2KB = 79.7 KB
// -> 2 blocks/CU preserved.
// --------------------------------------------------------------------------
__global__ __launch_bounds__(512, 4)
void k_score(const float* __restrict__ z, const float* __restrict__ W,
             const u16* __restrict__ Wsw,
             const float* __restrict__ inv_norm, const float* __restrict__ normW,
             int* __restrict__ mask, double* __restrict__ lacc) {
    __shared__ __align__(16) u16 A_sw[32768];   // [kc(8)][mt(8)][lane(64)][j(8)]
    __shared__ u32 bestk[128];
    __shared__ u32 cnt[128];                    // admission count -> status
    __shared__ u32 slots[128 * CAPL];           // (fix16 score<<16)|code -> cand codes
    __shared__ u32 ovfCnt;
    __shared__ u32 ovfList[128];
    __shared__ float gbv[32], gbp[32];
    __shared__ int   gbi[32];

    const int t    = threadIdx.x;
    const int lane = t & 63;
    const int w    = t >> 6;
    const size_t tok_base = (size_t)blockIdx.x * 128;

    if (t < 128) { bestk[t] = 0u; cnt[t] = 0u; }
    if (t == 0) ovfCnt = 0u;

    // ---- staging (l[2:0] -> m&7: conflict-free ds_write) + fused sum(z^2) --
    float ssq = 0.f;
#pragma unroll
    for (int i = 0; i < 8; i++) {
        const int m = ((i & 1) << 6) | (w << 3) | (lane & 7);    // token row
        const int o = ((i >> 1) << 3) | (lane >> 3);             // k-octet
        const float* zp = z + (tok_base + m) * E_DIM + o * 8;
        const float4 v0 = reinterpret_cast<const float4*>(zp)[0];
        const float4 v1 = reinterpret_cast<const float4*>(zp)[1];
        ssq += v0.x * v0.x + v0.y * v0.y + v0.z * v0.z + v0.w * v0.w
             + v1.x * v1.x + v1.y * v1.y + v1.z * v1.z + v1.w * v1.w;
        uint4 d;
        d.x = pk2fh(v0.x, v0.y);
        d.y = pk2fh(v0.z, v0.w);
        d.z = pk2fh(v1.x, v1.y);
        d.w = pk2fh(v1.z, v1.w);
        const int kc = o >> 2, q = o & 3, col = m & 15, mt = m >> 4;
        *reinterpret_cast<uint4*>(A_sw + ((size_t)((kc * 8 + mt) * 64 + q * 16 + col)) * 8) = d;
    }
#pragma unroll
    for (int sh = 1; sh < 64; sh <<= 1) ssq += __shfl_xor(ssq, sh, 64);
    if (lane == 0) atomicAdd(&lacc[(blockIdx.x * 8 + w) & 255], (double)ssq);
    __syncthreads();

    const int mq = w >> 2;                 // token half (64 tokens, mi=4)
    const int nq = w & 3;                  // code 64-group within chunk (ni=4)
    const int q = lane >> 4, col = lane & 15;
    const u16* wb = Wsw + ((size_t)((nq >> 1) * 64 + (nq & 1) * 4)) * 512
                        + (size_t)lane * 8;

    f32x4 acc[4][4];

#define ZERO_ACC() { _Pragma("unroll") for (int mi = 0; mi < 4; mi++) \
    _Pragma("unroll") for (int ni = 0; ni < 4; ni++) { \
        f32x4 zf = {0.f, 0.f, 0.f, 0.f}; acc[mi][ni] = zf; } }

#define KLOOP(NB2) { \
    __builtin_amdgcn_s_setprio(1); \
    _Pragma("unroll 4") \
    for (int kc = 0; kc < 8; kc++) { \
        f16x8 bf[4], af[4]; \
        _Pragma("unroll") for (int ni = 0; ni < 4; ni++) \
            bf[ni] = *reinterpret_cast<const f16x8*>( \
                wb + (size_t)((NB2) * 128 + kc * 8 + ni) * 512); \
        _Pragma("unroll") for (int mi = 0; mi < 4; mi++) \
            af[mi] = *reinterpret_cast<const f16x8*>( \
                A_sw + ((size_t)((kc * 8 + mq * 4 + mi) * 64 + lane)) * 8); \
        _Pragma("unroll") for (int mi = 0; mi < 4; mi++) \
        _Pragma("unroll") for (int ni = 0; ni < 4; ni++) \
            acc[mi][ni] = __builtin_amdgcn_mfma_f32_16x16x32_f16( \
                af[mi], bf[ni], acc[mi][ni], 0, 0, 0); } \
    __builtin_amdgcn_s_setprio(0); }

// max-prescreen: one fused max + compare skips the branchy per-ni admission
// checks (and folds 4 atomicMax into 1) in the common no-admission case.
#define ADMIT(NB2, DO_MAX) { \
    _Pragma("unroll") for (int mi = 0; mi < 4; mi++) \
    _Pragma("unroll") for (int r = 0; r < 4; r++) { \
        const int tk = mq * 64 + mi * 16 + q * 4 + r; \
        const float thr = keydec(bestk[tk]) - D_ADM; \
        const float vmax = fmaxf(fmaxf(acc[mi][0][r], acc[mi][1][r]), \
                                 fmaxf(acc[mi][2][r], acc[mi][3][r])); \
        if (vmax >= thr) { \
            if (DO_MAX) atomicMax(&bestk[tk], keyenc(vmax)); \
            _Pragma("unroll") for (int ni = 0; ni < 4; ni++) { \
                const float v = acc[mi][ni][r]; \
                if (v >= thr) { \
                    const int code = ((NB2) * 16 + nq * 4 + ni) * 16 + col; \
                    const u32 sl = atomicAdd(&cnt[tk], 1u); \
                    if (sl < CAPL) { \
                        const float vc = fminf(fmaxf((v + 16.f) * 2048.f, 0.f), 65535.f); \
                        slots[tk * CAPL + sl] = ((u32)vc << 16) | (u32)code; \
                    } } } } } }

    // ---- chunk 0: compute, tight bestk (shfl chains + ONE barrier), admit --
    ZERO_ACC();
    KLOOP(0);
#pragma unroll
    for (int mi = 0; mi < 4; mi++)
#pragma unroll
        for (int r = 0; r < 4; r++) {
            float m0 = fmaxf(fmaxf(acc[mi][0][r], acc[mi][1][r]),
                             fmaxf(acc[mi][2][r], acc[mi][3][r]));
#pragma unroll
            for (int sh = 1; sh < 16; sh <<= 1)
                m0 = fmaxf(m0, __shfl_xor(m0, sh, 64));
            if (col == 0)
                atomicMax(&bestk[mq * 64 + mi * 16 + q * 4 + r], keyenc(m0));
        }
    __syncthreads();   // bestk now tight over 256 codes
    ADMIT(0, 0);

    // ---- chunks 1-3: barrier-free streaming (stale bestk only loosens
    // admission; the true winner always passes) ----
#pragma unroll 1
    for (int nb2 = 1; nb2 < 4; nb2++) {
        ZERO_ACC();
        KLOOP(nb2);
        ADMIT(nb2, 1);
    }
#undef ZERO_ACC
#undef KLOOP
#undef ADMIT

    __syncthreads();
    // ---- compaction: m==1 -> finish via loss identity; 2..CAPG -> status=m
    //      (cands rewritten into own slots row); else -> overflow list ----
    if (t < 128) {
        const u32 c = cnt[t];
        const float best = keydec(bestk[t]);
        u32 status = 0u;
        float xacc = 0.f;
        if (c > CAPL) {
            const u32 p = atomicAdd(&ovfCnt, 1u);
            ovfList[p] = (u32)t;
            status = 0xFFFFFFFFu;
        } else {
            const float thrf = best - D_FIL;
            u32 loc[CAPG]; u32 m = 0;
            for (u32 i = 0; i < c; i++) {
                const u32 s2 = slots[t * CAPL + i];
                const float ap = (float)(s2 >> 16) * (1.0f / 2048.0f) - 16.0f;
                if (ap >= thrf) { if (m < CAPG) loc[m] = s2 & 0xFFFFu; m++; }
            }
            if (m == 1) {
                const int bi = (int)loc[0];
                mask[bi] = 1;                            // benign race
                const float nw = normW[bi];
                xacc = fmaf(-2.0f * best, nw, nw * nw);  // -2 z.Wbi + |Wbi|^2
            } else if (m <= CAPG) {
                for (u32 i = 0; i < m; i++) slots[t * CAPL + i] = loc[i];
                status = m;
            } else {
                const u32 p = atomicAdd(&ovfCnt, 1u);
                ovfList[p] = (u32)t;
                status = 0xFFFFFFFFu;
            }
        }
        cnt[t] = status;
        float xs = xacc;
#pragma unroll
        for (int sh = 1; sh < 64; sh <<= 1) xs += __shfl_xor(xs, sh, 64);
        if (lane == 0) atomicAdd(&lacc[(blockIdx.x * 2 + w) & 255], (double)xs);
    }
    __syncthreads();

    // ---- in-block ambiguous resolve: 32 x 16-lane groups, 4 tokens each.
    //      Exact f32 rescore, op order identical to the old k_pick. ----
    {
        const int gl = t & 15, grp = t >> 4;
#pragma unroll 1
        for (int it = 0; it < 4; ++it) {
            const int tk = grp * 4 + it;
            const u32 m = cnt[tk];
            if (m >= 2u && m <= (u32)CAPG) {
                const size_t tok = tok_base + tk;
                float4 zv[4];
#pragma unroll
                for (int j = 0; j < 4; j++)
                    zv[j] = reinterpret_cast<const float4*>(z + tok * E_DIM)[j * 16 + gl];
                float bv = -3.4e38f, bp = 0.f;
                int bi = 0x7FFFFFFF;
#pragma unroll 1
                for (u32 k2 = 0; k2 < m; k2++) {
                    const int c = (int)slots[tk * CAPL + k2];
                    float p = 0.f;
#pragma unroll
                    for (int j = 0; j < 4; j++) {
                        const float4 wv = reinterpret_cast<const float4*>(W + (size_t)c * E_DIM)[j * 16 + gl];
                        p += zv[j].x * wv.x + zv[j].y * wv.y + zv[j].z * wv.z + zv[j].w * wv.w;
                    }
#pragma unroll
                    for (int sh = 1; sh < 16; sh <<= 1) p += __shfl_xor(p, sh, 64);
                    const float s = p * inv_norm[c];
                    if (s > bv || (s == bv && c < bi)) { bv = s; bi = c; bp = p; }
                }
                if (gl == 0) {
                    mask[bi] = 1;
                    atomicAdd(&lacc[(u32)tok & 255],
                              (double)fmaf(-2.0f, bp, normW[bi] * normW[bi]));
                }
            }
        }
    }

    // ---- in-block overflow resolve (rare): block-wide exact full scan,
    //      32 groups x 32 codes, LDS merge with ascending-index ties. ----
    {
        const int gl = t & 15, grp = t >> 4;
        const u32 novf = ovfCnt;           // stable since pre-barrier write
#pragma unroll 1
        for (u32 i = 0; i < novf; ++i) {
            const int tk = (int)ovfList[i];
            const size_t tok = tok_base + tk;
            float4 zv[4];
#pragma unroll
            for (int j = 0; j < 4; j++)
                zv[j] = reinterpret_cast<const float4*>(z + tok * E_DIM)[j * 16 + gl];
            float bv = -3.4e38f, bp = 0.f;
            int bi = 0x7FFFFFFF;
#pragma unroll 1
            for (int k2 = 0; k2 < 32; ++k2) {
                const int c = grp * 32 + k2;
                float p = 0.f;
#pragma unroll
                for (int j = 0; j < 4; j++) {
                    const float4 wv = reinterpret_cast<const float4*>(W + (size_t)c * E_DIM)[j * 16 + gl];
                    p += zv[j].x * wv.x + zv[j].y * wv.y + zv[j].z * wv.z + zv[j].w * wv.w;
                }
#pragma unroll
                for (int sh = 1; sh < 16; sh <<= 1) p += __shfl_xor(p, sh, 64);
                const float s = p * inv_norm[c];
                if (s > bv || (s == bv && c < bi)) { bv = s; bi = c; bp = p; }
            }
            if (gl == 0) { gbv[grp] = bv; gbi[grp] = bi; gbp[grp] = bp; }
            __syncthreads();
            if (t == 0) {
                float fb = gbv[0], fp = gbp[0];
                int fi = gbi[0];
                for (int g2 = 1; g2 < 32; g2++) {
                    const float v2 = gbv[g2];
                    const int i2 = gbi[g2];
                    if (v2 > fb || (v2 == fb && i2 < fi)) { fb = v2; fi = i2; fp = gbp[g2]; }
                }
                mask[fi] = 1;
                atomicAdd(&lacc[(u32)tok & 255],
                          (double)fmaf(-2.0f, fp, normW[fi] * normW[fi]));
            }
            __syncthreads();   // protect gbv/gbi/gbp reuse next iteration
        }
    }
}

// --------------------------------------------------------------------------
// K4 emit (fused rank): each block redundantly reduces mask for prefix(e)
// and total; writes emb row + label. Block 0 finalizes loss.
// --------------------------------------------------------------------------
__global__ __launch_bounds__(256)
void k_emit(const float* __restrict__ W, const int* __restrict__ mask,
            const double* __restrict__ lacc, float* __restrict__ out) {
    __shared__ int    redp[256], redt[256];
    __shared__ double dred[256];
    const int e = blockIdx.x;              // 1024
    const int t = threadIdx.x;             // 256
    const int4 mv = reinterpret_cast<const int4*>(mask)[t];
    const int b = t * 4;
    redt[t] = mv.x + mv.y + mv.z + mv.w;
    redp[t] = (b + 0 < e ? mv.x : 0) + (b + 1 < e ? mv.y : 0) +
              (b + 2 < e ? mv.z : 0) + (b + 3 < e ? mv.w : 0);
    if (e == 0) dred[t] = lacc[t];
    __syncthreads();
#pragma unroll
    for (int s2 = 128; s2 > 0; s2 >>= 1) {
        if (t < s2) {
            redp[t] += redp[t + s2];
            redt[t] += redt[t + s2];
            if (e == 0) dred[t] += dred[t + s2];
        }
        __syncthreads();
    }
    const int prefix = redp[0], total = redt[0];
    const int m = mask[e];
    const int r = m ? prefix : (total + e - prefix);
    out[(size_t)r * E_DIM + t] = W[(size_t)e * E_DIM + t];
    if (t == 0) out[(size_t)N_E * E_DIM + r] = m ? 1.0f : 0.0f;
    if (e == 0 && t == 0) {
        const double mse = dred[0] / (double)((size_t)N_TOK * E_DIM);
        out[(size_t)N_E * E_DIM + N_E] = (float)((1.0 + (double)BETA) * mse);
    }
}

// --------------------------------------------------------------------------
extern "C" void kernel_launch(void* const* d_in, const int* in_sizes, int n_in,
                              void* d_out, int out_size, void* d_ws, size_t ws_size,
                              hipStream_t stream) {
    const float* z = (const float*)d_in[0];
    const float* W = (const float*)d_in[1];
    float* out = (float*)d_out;
    char* ws = (char*)d_ws;

    float*  inv_norm = (float*)(ws + WS_INVNORM);
    float*  normW    = (float*)(ws + WS_NORMW);
    int*    mask     = (int*)(ws + WS_MASK);
    double* lacc     = (double*)(ws + WS_LACC);
    u16*    Wsw      = (u16*)(ws + WS_WSW);

    k_prep <<<N_E, 64, 0, stream>>>(W, Wsw, inv_norm, normW, mask, lacc);
    k_score<<<N_TOK / 128, 512, 0, stream>>>(z, W, Wsw, inv_norm, normW,
                                             mask, lacc);
    k_emit <<<N_E, 256, 0, stream>>>(W, mask, lacc, out);
}